// Round 3
// baseline (284.696 us; speedup 1.0000x reference)
//
#include <hip/hip_runtime.h>
#include <cstdint>

typedef unsigned short u16;
using bf16x8 = __attribute__((ext_vector_type(8))) short;
using u16x8  = __attribute__((ext_vector_type(8))) unsigned short;
using f32x4  = __attribute__((ext_vector_type(4))) float;

#define DM 1024

__device__ __forceinline__ u16 f2b(float f) {
    union { float f; unsigned u; } v; v.f = f;
    unsigned r = v.u + 0x7FFFu + ((v.u >> 16) & 1u);   // round-to-nearest-even
    return (u16)(r >> 16);
}
__device__ __forceinline__ float b2f(u16 b) {
    union { unsigned u; float f; } v; v.u = ((unsigned)b) << 16;
    return v.f;
}

// global -> LDS direct (16B/lane). LDS dest is wave-uniform base + lane*16.
#define GLL(gp, lp) __builtin_amdgcn_global_load_lds( \
    (const __attribute__((address_space(1))) void*)(uintptr_t)(gp), \
    (__attribute__((address_space(3))) void*)(unsigned)(uintptr_t)(lp), 16, 0, 0)

#define BAR()    __builtin_amdgcn_s_barrier()
#define WAITV4() asm volatile("s_waitcnt vmcnt(4)" ::: "memory")
#define WAITV0() asm volatile("s_waitcnt vmcnt(0)" ::: "memory")

// ---------------- fused f32 -> bf16 convert for all 5 inputs ----------------
__global__ __launch_bounds__(256) void cvt_all(const float* __restrict__ x,
                                               const float* __restrict__ Wq,
                                               const float* __restrict__ Wk,
                                               const float* __restrict__ Wv,
                                               const float* __restrict__ Wo,
                                               u16* __restrict__ xb,
                                               u16* __restrict__ wqkv,
                                               u16* __restrict__ wob) {
    size_t v = ((size_t)blockIdx.x * 256 + threadIdx.x) << 3;
    const float* src; u16* dst; size_t off;
    if (v < (size_t)4194304) { src = x; dst = xb; off = v; }
    else {
        size_t w = v - 4194304; int s = (int)(w >> 20); off = w & 1048575;
        src = (s == 0) ? Wq : (s == 1) ? Wk : (s == 2) ? Wv : Wo;
        dst = (s < 3) ? (wqkv + ((size_t)s << 20)) : wob;
    }
    const f32x4* p = (const f32x4*)(src + off);
    f32x4 a = p[0], b = p[1];
    u16x8 o;
    o[0] = f2b(a[0]); o[1] = f2b(a[1]); o[2] = f2b(a[2]); o[3] = f2b(a[3]);
    o[4] = f2b(b[0]); o[5] = f2b(b[1]); o[6] = f2b(b[2]); o[7] = f2b(b[3]);
    *(u16x8*)(dst + off) = o;
}

// ---------------- 256x256-tile 8-phase bf16 GEMM, K=1024, C = A @ B^T ----------------
#define MROW(af_, bf_, d) \
    acc[d][0] = __builtin_amdgcn_mfma_f32_16x16x32_bf16(af_, bf_[0], acc[d][0], 0, 0, 0); \
    acc[d][1] = __builtin_amdgcn_mfma_f32_16x16x32_bf16(af_, bf_[1], acc[d][1], 0, 0, 0); \
    acc[d][2] = __builtin_amdgcn_mfma_f32_16x16x32_bf16(af_, bf_[2], acc[d][2], 0, 0, 0); \
    acc[d][3] = __builtin_amdgcn_mfma_f32_16x16x32_bf16(af_, bf_[3], acc[d][3], 0, 0, 0);

#define MFMA16(af_, bf_, ib) do { \
    __builtin_amdgcn_s_setprio(1); \
    MROW(af_[0], bf_, (ib) + 0) \
    MROW(af_[1], bf_, (ib) + 1) \
    MROW(af_[2], bf_, (ib) + 2) \
    MROW(af_[3], bf_, (ib) + 3) \
    __builtin_amdgcn_s_setprio(0); } while (0)

__global__ __launch_bounds__(512, 2) void gemm_qkv8(const u16* __restrict__ A,
                                                    const u16* __restrict__ B,
                                                    u16* __restrict__ Q,
                                                    u16* __restrict__ Ko,
                                                    u16* __restrict__ V) {
    __shared__ __align__(16) u16 As[2 * 16384];   // 64 KB: [buf][256][64]
    __shared__ __align__(16) u16 Bs[2 * 16384];   // 64 KB
    const int tid  = threadIdx.x;
    const int lane = tid & 63;
    const int wid  = tid >> 6;
    const int wr   = wid >> 2;          // 0..1
    const int wc   = wid & 3;           // 0..3
    const int fr   = lane & 15;
    const int fg   = lane >> 4;
    const int brow = blockIdx.y << 8;
    const int bcol = blockIdx.x << 8;

    const int srow = tid >> 3;                           // 0..63
    const int scol = ((tid & 7) ^ (srow & 7)) << 3;      // 0..56
    const u16* Ag = A + (size_t)(brow + srow) * 1024 + scol;
    const u16* Bg = B + (size_t)(bcol + srow) * 1024 + scol;

#define STG_A(buf, kt, c) GLL(Ag + (size_t)(c) * 65536 + (kt) * 64, \
                              (char*)As + (buf) * 32768 + (c) * 8192 + (wid << 10))
#define STG_B(buf, kt, c) GLL(Bg + (size_t)(c) * 65536 + (kt) * 64, \
                              (char*)Bs + (buf) * 32768 + (c) * 8192 + (wid << 10))

    const int swz  = (fr & 7) << 3;
    const int col0 = (fg << 3) ^ swz;          // k-step 0
    const int col1 = (32 + (fg << 3)) ^ swz;   // k-step 1
    const int aro  = ((wr << 7) + fr) << 6;
    const int bro  = ((wc << 6) + fr) << 6;

#define LDA4(dst, bufo, ih, cl) do { \
    const u16* p_ = As + (bufo) + aro + ((ih) << 12) + (cl); \
    dst[0] = *(const bf16x8*)(p_); \
    dst[1] = *(const bf16x8*)(p_ + 1024); \
    dst[2] = *(const bf16x8*)(p_ + 2048); \
    dst[3] = *(const bf16x8*)(p_ + 3072); } while (0)

#define LDB4(dst, bufo, cl) do { \
    const u16* p_ = Bs + (bufo) + bro + (cl); \
    dst[0] = *(const bf16x8*)(p_); \
    dst[1] = *(const bf16x8*)(p_ + 1024); \
    dst[2] = *(const bf16x8*)(p_ + 2048); \
    dst[3] = *(const bf16x8*)(p_ + 3072); } while (0)

    f32x4 acc[8][4];
    const f32x4 z = {0.f, 0.f, 0.f, 0.f};
    #pragma unroll
    for (int i = 0; i < 8; ++i)
        #pragma unroll
        for (int j = 0; j < 4; ++j) acc[i][j] = z;

    bf16x8 af0[4], af1[4], bf0[4], bf1[4];

    STG_B(0, 0, 0); STG_B(0, 0, 1); STG_B(0, 0, 2); STG_B(0, 0, 3);
    STG_A(0, 0, 0); STG_A(0, 0, 1); STG_A(0, 0, 2); STG_A(0, 0, 3);
    STG_B(1, 1, 0); STG_B(1, 1, 1); STG_B(1, 1, 2); STG_B(1, 1, 3);
    WAITV4();
    BAR();

    #pragma unroll 1
    for (int t = 0; t < 7; ++t) {
        const int k1 = 2 * t + 1, k2 = 2 * t + 2, k3 = 2 * t + 3;
        LDA4(af0, 0, 0, col0); LDB4(bf0, 0, col0);
        STG_A(1, k1, 0); STG_A(1, k1, 1);
        BAR(); MFMA16(af0, bf0, 0); BAR();
        LDA4(af1, 0, 0, col1); LDB4(bf1, 0, col1);
        STG_A(1, k1, 2); STG_A(1, k1, 3);
        BAR(); MFMA16(af1, bf1, 0); BAR();
        LDA4(af0, 0, 1, col0);
        STG_B(0, k2, 0); STG_B(0, k2, 1);
        BAR(); MFMA16(af0, bf0, 4); BAR();
        LDA4(af1, 0, 1, col1);
        STG_B(0, k2, 2); STG_B(0, k2, 3);
        BAR(); MFMA16(af1, bf1, 4); WAITV4(); BAR();
        LDA4(af0, 16384, 0, col0); LDB4(bf0, 16384, col0);
        STG_A(0, k2, 0); STG_A(0, k2, 1);
        BAR(); MFMA16(af0, bf0, 0); BAR();
        LDA4(af1, 16384, 0, col1); LDB4(bf1, 16384, col1);
        STG_A(0, k2, 2); STG_A(0, k2, 3);
        BAR(); MFMA16(af1, bf1, 0); BAR();
        LDA4(af0, 16384, 1, col0);
        STG_B(1, k3, 0); STG_B(1, k3, 1);
        BAR(); MFMA16(af0, bf0, 4); BAR();
        LDA4(af1, 16384, 1, col1);
        STG_B(1, k3, 2); STG_B(1, k3, 3);
        BAR(); MFMA16(af1, bf1, 4); WAITV4(); BAR();
    }
    LDA4(af0, 0, 0, col0); LDB4(bf0, 0, col0);
    STG_A(1, 15, 0); STG_A(1, 15, 1);
    BAR(); MFMA16(af0, bf0, 0); BAR();
    LDA4(af1, 0, 0, col1); LDB4(bf1, 0, col1);
    STG_A(1, 15, 2); STG_A(1, 15, 3);
    BAR(); MFMA16(af1, bf1, 0); BAR();
    LDA4(af0, 0, 1, col0);
    BAR(); MFMA16(af0, bf0, 4); BAR();
    LDA4(af1, 0, 1, col1);
    BAR(); MFMA16(af1, bf1, 4); WAITV0(); BAR();
    LDA4(af0, 16384, 0, col0); LDB4(bf0, 16384, col0);
    BAR(); MFMA16(af0, bf0, 0); BAR();
    LDA4(af1, 16384, 0, col1); LDB4(bf1, 16384, col1);
    BAR(); MFMA16(af1, bf1, 0); BAR();
    LDA4(af0, 16384, 1, col0);
    BAR(); MFMA16(af0, bf0, 4); BAR();
    LDA4(af1, 16384, 1, col1);
    BAR(); MFMA16(af1, bf1, 4);

    const int which = bcol >> 10;
    u16* O = (which == 0) ? Q : ((which == 1) ? Ko : V);
    const int ocol0 = (bcol & 1023) + (wc << 6);
    const int orow0 = brow + (wr << 7);
    #pragma unroll
    for (int i = 0; i < 8; ++i)
        #pragma unroll
        for (int j = 0; j < 4; ++j)
            #pragma unroll
            for (int r = 0; r < 4; ++r) {
                const int row = orow0 + i * 16 + fg * 4 + r;
                const int col = ocol0 + j * 16 + fr;
                O[(size_t)row * 1024 + col] = f2b(acc[i][j][r]);
            }
#undef STG_A
#undef STG_B
#undef LDA4
#undef LDB4
}

// ---------------- 128x128-tile bf16 GEMM core (m97 structure), K=1024 ----------------
__device__ __forceinline__ void gemm_core_1024(const u16* __restrict__ A,
                                               const u16* __restrict__ B,
                                               int brow, int bcol,
                                               u16* Asb, u16* Bsb,
                                               f32x4 acc[4][4]) {
    const int tid  = threadIdx.x;
    const int lane = tid & 63;
    const int wid  = tid >> 6;
    const int wrow = (wid >> 1) << 6;
    const int wcol = (wid & 1) << 6;
    const int fr   = lane & 15;
    const int fk   = (lane >> 4) << 3;

    const size_t aBase = (size_t)(brow + (tid >> 2)) * 1024 + ((tid & 3) << 3);
    const size_t bBase = (size_t)(bcol + (tid >> 2)) * 1024 + ((tid & 3) << 3);
    const int wOff = wid << 10;

    const f32x4 z = {0.f, 0.f, 0.f, 0.f};
    #pragma unroll
    for (int i = 0; i < 4; ++i)
        #pragma unroll
        for (int j = 0; j < 4; ++j) acc[i][j] = z;

#define STAGE(bufi, kt) do { \
        const u16* ga_ = A + aBase + ((size_t)(kt) << 5); \
        const u16* gb_ = B + bBase + ((size_t)(kt) << 5); \
        char* la_ = (char*)(Asb + ((bufi) << 12)) + wOff; \
        char* lb_ = (char*)(Bsb + ((bufi) << 12)) + wOff; \
        GLL(ga_, la_); GLL(ga_ + (size_t)64 * 1024, la_ + 4096); \
        GLL(gb_, lb_); GLL(gb_ + (size_t)64 * 1024, lb_ + 4096); \
    } while (0)

    STAGE(0, 0);
    #pragma unroll 2
    for (int kt = 0; kt < 32; ++kt) {
        const int buf = kt & 1;
        __syncthreads();
        if (kt + 1 < 32) STAGE(buf ^ 1, kt + 1);
        const u16* As = Asb + (buf << 12);
        const u16* Bs = Bsb + (buf << 12);
        bf16x8 af[4], bfr[4];
        #pragma unroll
        for (int i = 0; i < 4; ++i)
            af[i] = *(const bf16x8*)(As + ((wrow + (i << 4) + fr) << 5) + fk);
        #pragma unroll
        for (int j = 0; j < 4; ++j)
            bfr[j] = *(const bf16x8*)(Bs + ((wcol + (j << 4) + fr) << 5) + fk);
        #pragma unroll
        for (int i = 0; i < 4; ++i)
            #pragma unroll
            for (int j = 0; j < 4; ++j)
                acc[i][j] = __builtin_amdgcn_mfma_f32_16x16x32_bf16(af[i], bfr[j], acc[i][j], 0, 0, 0);
    }
#undef STAGE
}

__global__ __launch_bounds__(256) void gemm_out(const u16* __restrict__ A,
                                                const u16* __restrict__ B,
                                                float* __restrict__ C) {
    __shared__ __align__(16) u16 As[2 * 128 * 32];
    __shared__ __align__(16) u16 Bs[2 * 128 * 32];
    const int brow = blockIdx.y << 7;
    const int bcol = blockIdx.x << 7;
    f32x4 acc[4][4];
    gemm_core_1024(A, B, brow, bcol, As, Bs, acc);

    const int lane = threadIdx.x & 63;
    const int wid  = threadIdx.x >> 6;
    const int wrow = (wid >> 1) << 6;
    const int wcol = (wid & 1) << 6;
    const int g = lane >> 4, c = lane & 15;
    #pragma unroll
    for (int i = 0; i < 4; ++i)
        #pragma unroll
        for (int j = 0; j < 4; ++j)
            #pragma unroll
            for (int r = 0; r < 4; ++r) {
                const int row = brow + wrow + i * 16 + g * 4 + r;
                const int col = bcol + wcol + j * 16 + c;
                C[(size_t)row * 1024 + col] = acc[i][j][r];
            }
}

// ---------------- sliding-window attention ----------------
__global__ __launch_bounds__(256) void attn_kernel(const u16* __restrict__ Qg,
                                                   const u16* __restrict__ Kg,
                                                   const u16* __restrict__ Vg,
                                                   u16* __restrict__ Og) {
    const int qb  = blockIdx.x;
    const int h   = blockIdx.y;
    const int tid = threadIdx.x;
    const int lane = tid & 63;
    const int w  = tid >> 6;
    const int fr = lane & 15;
    const int fg = lane >> 4;

    __shared__ __align__(16) u16 QK[64 * 72 + 128 * 72];
    __shared__ __align__(16) u16 Vt[64 * 136];
    __shared__ float Mrow[64][4];
    __shared__ float Lrow[64][4];

    u16* Qs = QK;
    u16* Ks = QK + 64 * 72;
    u16* Ps = QK;

    const int hoff  = h * 64;
    const int qrow0 = qb * 64;
    const int krow0 = qrow0 - 64;

    {
        const int r  = tid >> 3;
        const int c0 = (tid & 7) * 8;
        #pragma unroll
        for (int it = 0; it < 2; ++it) {
            const int row = r + it * 32;
            u16x8 val = *(const u16x8*)(Qg + (size_t)(qrow0 + row) * DM + hoff + c0);
            u16x8 o;
            #pragma unroll
            for (int e = 0; e < 8; ++e) o[e] = f2b(b2f(val[e]) * 0.125f);
            *(u16x8*)(Qs + row * 72 + c0) = o;
        }
        #pragma unroll
        for (int it = 0; it < 4; ++it) {
            const int row  = r + it * 32;
            const int grow = krow0 + row;
            u16x8 val = {0, 0, 0, 0, 0, 0, 0, 0};
            if (grow >= 0) val = *(const u16x8*)(Kg + (size_t)grow * DM + hoff + c0);
            *(u16x8*)(Ks + row * 72 + c0) = val;
        }
        #pragma unroll
        for (int it = 0; it < 4; ++it) {
            const int j    = r + it * 32;
            const int grow = krow0 + j;
            u16x8 val = {0, 0, 0, 0, 0, 0, 0, 0};
            if (grow >= 0) val = *(const u16x8*)(Vg + (size_t)grow * DM + hoff + c0);
            #pragma unroll
            for (int e = 0; e < 8; ++e) Vt[(c0 + e) * 136 + j] = val[e];
        }
    }
    __syncthreads();

    const f32x4 z = {0.f, 0.f, 0.f, 0.f};
    f32x4 s[4][2];
    #pragma unroll
    for (int i = 0; i < 4; ++i) { s[i][0] = z; s[i][1] = z; }
    #pragma unroll
    for (int kk = 0; kk < 2; ++kk) {
        const int k0 = kk * 32 + fg * 8;
        bf16x8 aq[4];
        #pragma unroll
        for (int i = 0; i < 4; ++i)
            aq[i] = *(const bf16x8*)(Qs + (i * 16 + fr) * 72 + k0);
        #pragma unroll
        for (int n = 0; n < 2; ++n) {
            const bf16x8 bk = *(const bf16x8*)(Ks + (w * 32 + n * 16 + fr) * 72 + k0);
            #pragma unroll
            for (int i = 0; i < 4; ++i)
                s[i][n] = __builtin_amdgcn_mfma_f32_16x16x32_bf16(aq[i], bk, s[i][n], 0, 0, 0);
        }
    }

    #pragma unroll
    for (int i = 0; i < 4; ++i) {
        #pragma unroll
        for (int r = 0; r < 4; ++r) {
            const int irow = i * 16 + fg * 4 + r;
            float mx = -3.0e38f;
            #pragma unroll
            for (int n = 0; n < 2; ++n) {
                const int jcol = w * 32 + n * 16 + fr;
                const bool valid = (jcol >= irow + 1) && (jcol <= irow + 64) && (krow0 + jcol >= 0);
                const float v = valid ? s[i][n][r] : -3.0e38f;
                s[i][n][r] = v;
                mx = fmaxf(mx, v);
            }
            #pragma unroll
            for (int d = 1; d < 16; d <<= 1) mx = fmaxf(mx, __shfl_xor(mx, d));
            if (fr == 0) Mrow[irow][w] = mx;
        }
    }
    __syncthreads();

    #pragma unroll
    for (int i = 0; i < 4; ++i) {
        #pragma unroll
        for (int r = 0; r < 4; ++r) {
            const int irow = i * 16 + fg * 4 + r;
            const float M = fmaxf(fmaxf(Mrow[irow][0], Mrow[irow][1]),
                                  fmaxf(Mrow[irow][2], Mrow[irow][3]));
            float sum = 0.f;
            #pragma unroll
            for (int n = 0; n < 2; ++n) {
                const float v = s[i][n][r];
                const float p = (v > -1.0e38f) ? __expf(v - M) : 0.f;
                sum += p;
                Ps[irow * 136 + (w * 32 + n * 16 + fr)] = f2b(p);
            }
            #pragma unroll
            for (int d = 1; d < 16; d <<= 1) sum += __shfl_xor(sum, d);
            if (fr == 0) Lrow[irow][w] = sum;
        }
    }
    __syncthreads();

    f32x4 o[4] = {z, z, z, z};
    #pragma unroll
    for (int ks = 0; ks < 4; ++ks) {
        const int k0 = ks * 32 + fg * 8;
        const bf16x8 ap = *(const bf16x8*)(Ps + (w * 16 + fr) * 136 + k0);
        #pragma unroll
        for (int n = 0; n < 4; ++n) {
            const bf16x8 bv = *(const bf16x8*)(Vt + (n * 16 + fr) * 136 + k0);
            o[n] = __builtin_amdgcn_mfma_f32_16x16x32_bf16(ap, bv, o[n], 0, 0, 0);
        }
    }

    #pragma unroll
    for (int r = 0; r < 4; ++r) {
        const int irow = w * 16 + fg * 4 + r;
        const float L = Lrow[irow][0] + Lrow[irow][1] + Lrow[irow][2] + Lrow[irow][3];
        const float rl = 1.0f / L;
        #pragma unroll
        for (int n = 0; n < 4; ++n)
            Og[(size_t)(qrow0 + irow) * DM + hoff + n * 16 + fr] = f2b(o[n][r] * rl);
    }
}

extern "C" void kernel_launch(void* const* d_in, const int* in_sizes, int n_in,
                              void* d_out, int out_size, void* d_ws, size_t ws_size,
                              hipStream_t stream) {
    (void)in_sizes; (void)n_in; (void)out_size; (void)ws_size;
    const float* x  = (const float*)d_in[0];
    const float* Wq = (const float*)d_in[1];
    const float* Wk = (const float*)d_in[2];
    const float* Wv = (const float*)d_in[3];
    const float* Wo = (const float*)d_in[4];
    float* out = (float*)d_out;

    char* ws = (char*)d_ws;
    u16* xb   = (u16*)(ws);                             // 8 MB  [4096][1024]
    u16* Wqkv = (u16*)(ws + ((size_t)8  << 20));        // 6 MB  [3072][1024]
    u16* Wob  = (u16*)(ws + ((size_t)14 << 20));        // 2 MB
    u16* qb   = (u16*)(ws + ((size_t)16 << 20));        // 8 MB
    u16* kb   = (u16*)(ws + ((size_t)24 << 20));        // 8 MB
    u16* vb   = (u16*)(ws + ((size_t)32 << 20));        // 8 MB
    u16* ab   = (u16*)(ws + ((size_t)40 << 20));        // 8 MB

    // DIAGNOSTIC ROUND: idempotent replays for timing attribution.
    // dur = base + 5*t(gemm_qkv8) + 2*t(attn). All kernels byte-identical to R2.
    cvt_all<<<4096, 256, 0, stream>>>(x, Wq, Wk, Wv, Wo, xb, Wqkv, Wob);
    for (int r = 0; r < 6; ++r)
        gemm_qkv8<<<dim3(12, 16), 512, 0, stream>>>(xb, Wqkv, qb, kb, vb);
    for (int r = 0; r < 3; ++r)
        attn_kernel<<<dim3(64, 16), 256, 0, stream>>>(qb, kb, vb, ab);
    gemm_out<<<dim3(8, 32), 256, 0, stream>>>(ab, Wob, out);
}

// Round 4
// 85.675 us; speedup vs baseline: 3.3230x; 3.3230x over previous
//
#include <hip/hip_runtime.h>
#include <cstdint>

typedef unsigned short u16;
using bf16x8 = __attribute__((ext_vector_type(8))) short;
using u16x8  = __attribute__((ext_vector_type(8))) unsigned short;
using f32x4  = __attribute__((ext_vector_type(4))) float;

#define DM 1024

__device__ __forceinline__ u16 f2b(float f) {
    union { float f; unsigned u; } v; v.f = f;
    unsigned r = v.u + 0x7FFFu + ((v.u >> 16) & 1u);   // round-to-nearest-even
    return (u16)(r >> 16);
}
__device__ __forceinline__ float b2f(u16 b) {
    union { unsigned u; float f; } v; v.u = ((unsigned)b) << 16;
    return v.f;
}

#define GLL(gp, lp) __builtin_amdgcn_global_load_lds( \
    (const __attribute__((address_space(1))) void*)(uintptr_t)(gp), \
    (__attribute__((address_space(3))) void*)(unsigned)(uintptr_t)(lp), 16, 0, 0)

#define BAR()    __builtin_amdgcn_s_barrier()
#define WAITV3() asm volatile("s_waitcnt vmcnt(3)" ::: "memory")
#define WAITV0() asm volatile("s_waitcnt vmcnt(0)" ::: "memory")

// ---------------- fused f32 -> bf16 convert for all 5 inputs ----------------
__global__ __launch_bounds__(256) void cvt_all(const float* __restrict__ x,
                                               const float* __restrict__ Wq,
                                               const float* __restrict__ Wk,
                                               const float* __restrict__ Wv,
                                               const float* __restrict__ Wo,
                                               u16* __restrict__ xb,
                                               u16* __restrict__ wqkv,
                                               u16* __restrict__ wob) {
    size_t v = ((size_t)blockIdx.x * 256 + threadIdx.x) << 3;
    const float* src; u16* dst; size_t off;
    if (v < (size_t)4194304) { src = x; dst = xb; off = v; }
    else {
        size_t w = v - 4194304; int s = (int)(w >> 20); off = w & 1048575;
        src = (s == 0) ? Wq : (s == 1) ? Wk : (s == 2) ? Wv : Wo;
        dst = (s < 3) ? (wqkv + ((size_t)s << 20)) : wob;
    }
    const f32x4* p = (const f32x4*)(src + off);
    f32x4 a = p[0], b = p[1];
    u16x8 o;
    o[0] = f2b(a[0]); o[1] = f2b(a[1]); o[2] = f2b(a[2]); o[3] = f2b(a[3]);
    o[4] = f2b(b[0]); o[5] = f2b(b[1]); o[6] = f2b(b[2]); o[7] = f2b(b[3]);
    *(u16x8*)(dst + off) = o;
}

// ---------------- 256x192-tile 8-phase bf16 GEMM, K=1024 ----------------
// C[4096][3072] = A @ Wqkv^T, output written to ONE contiguous buffer (stride 3072).
// 512 threads = 8 waves (2M x 4N). Wave owns 128x48. BK=64 dbuf. Grid 16x16 = 256 blocks.
// Staging: A = 4 chunks/K-tile, B = 3 chunks/K-tile (8KB each); waits vmcnt(3) at P4/P8.
#define MROW3(af_, bf_, d) \
    acc[d][0] = __builtin_amdgcn_mfma_f32_16x16x32_bf16(af_, bf_[0], acc[d][0], 0, 0, 0); \
    acc[d][1] = __builtin_amdgcn_mfma_f32_16x16x32_bf16(af_, bf_[1], acc[d][1], 0, 0, 0); \
    acc[d][2] = __builtin_amdgcn_mfma_f32_16x16x32_bf16(af_, bf_[2], acc[d][2], 0, 0, 0);

#define MFMA12(af_, bf_, ib) do { \
    __builtin_amdgcn_s_setprio(1); \
    MROW3(af_[0], bf_, (ib) + 0) \
    MROW3(af_[1], bf_, (ib) + 1) \
    MROW3(af_[2], bf_, (ib) + 2) \
    MROW3(af_[3], bf_, (ib) + 3) \
    __builtin_amdgcn_s_setprio(0); } while (0)

__global__ __launch_bounds__(512, 2) void gemm_qkv8(const u16* __restrict__ A,
                                                    const u16* __restrict__ B,
                                                    u16* __restrict__ QKV) {
    __shared__ __align__(16) u16 As[2 * 16384];   // 64 KB: [buf][256 rows][64]
    __shared__ __align__(16) u16 Bs[2 * 12288];   // 48 KB: [buf][192 rows][64]
    const int tid  = threadIdx.x;
    const int lane = tid & 63;
    const int wid  = tid >> 6;
    const int wr   = wid >> 2;          // 0..1
    const int wc   = wid & 3;           // 0..3
    const int fr   = lane & 15;
    const int fg   = lane >> 4;

    // bijective XCD swizzle: hw id -> logical tile id (256 blocks, 8 XCDs)
    const int hw   = blockIdx.y * 16 + blockIdx.x;
    const int lg   = (hw & 7) * 32 + (hw >> 3);
    const int brow = (lg >> 4) << 8;          // tileY * 256
    const int bcol = (lg & 15) * 192;         // tileX * 192

    const int srow = tid >> 3;                           // 0..63
    const int scol = ((tid & 7) ^ (srow & 7)) << 3;      // pre-swizzled source col
    const u16* Ag = A + (size_t)(brow + srow) * 1024 + scol;
    const u16* Bg = B + (size_t)(bcol + srow) * 1024 + scol;

#define STG_A(buf, kt, c) GLL(Ag + (size_t)(c) * 65536 + (kt) * 64, \
                              (char*)As + (buf) * 32768 + (c) * 8192 + (wid << 10))
#define STG_B(buf, kt, c) GLL(Bg + (size_t)(c) * 65536 + (kt) * 64, \
                              (char*)Bs + (buf) * 24576 + (c) * 8192 + (wid << 10))

    const int swz  = (fr & 7) << 3;
    const int col0 = (fg << 3) ^ swz;
    const int col1 = (32 + (fg << 3)) ^ swz;
    const int aro  = ((wr << 7) + fr) << 6;   // (wr*128+fr)*64
    const int bro  = ((wc * 48) + fr) << 6;   // (wc*48+fr)*64

#define LDA4(dst, bufo, ih, cl) do { \
    const u16* p_ = As + (bufo) + aro + ((ih) << 12) + (cl); \
    dst[0] = *(const bf16x8*)(p_); \
    dst[1] = *(const bf16x8*)(p_ + 1024); \
    dst[2] = *(const bf16x8*)(p_ + 2048); \
    dst[3] = *(const bf16x8*)(p_ + 3072); } while (0)

#define LDB3(dst, bufo, cl) do { \
    const u16* p_ = Bs + (bufo) + bro + (cl); \
    dst[0] = *(const bf16x8*)(p_); \
    dst[1] = *(const bf16x8*)(p_ + 1024); \
    dst[2] = *(const bf16x8*)(p_ + 2048); } while (0)

    f32x4 acc[8][3];
    const f32x4 z = {0.f, 0.f, 0.f, 0.f};
    #pragma unroll
    for (int i = 0; i < 8; ++i)
        #pragma unroll
        for (int j = 0; j < 3; ++j) acc[i][j] = z;

    bf16x8 af0[4], af1[4], bf0[3], bf1[3];

    // prologue: K0 full (7 chunks, oldest), then K1.B (3)
    STG_B(0, 0, 0); STG_B(0, 0, 1); STG_B(0, 0, 2);
    STG_A(0, 0, 0); STG_A(0, 0, 1); STG_A(0, 0, 2); STG_A(0, 0, 3);
    STG_B(1, 1, 0); STG_B(1, 1, 1); STG_B(1, 1, 2);
    WAITV3();
    BAR();

    #pragma unroll 1
    for (int t = 0; t < 7; ++t) {
        const int k1 = 2 * t + 1, k2 = 2 * t + 2, k3 = 2 * t + 3;
        // P1: compute buf0 Ah0/ks0; stage buf1.A c0,c1 (k1)
        LDA4(af0, 0, 0, col0); LDB3(bf0, 0, col0);
        STG_A(1, k1, 0); STG_A(1, k1, 1);
        BAR(); MFMA12(af0, bf0, 0); BAR();
        // P2: Ah0/ks1; stage buf1.A c2,c3
        LDA4(af1, 0, 0, col1); LDB3(bf1, 0, col1);
        STG_A(1, k1, 2); STG_A(1, k1, 3);
        BAR(); MFMA12(af1, bf1, 0); BAR();
        // P3: Ah1/ks0; stage buf0.B c0,c1 (k2) -- buf0 B-reads completed in P1/P2
        LDA4(af0, 0, 1, col0);
        STG_B(0, k2, 0); STG_B(0, k2, 1);
        BAR(); MFMA12(af0, bf0, 4); BAR();
        // P4: Ah1/ks1; stage buf0.B c2; wait: k1 landed (3 newest = k2.B stay in flight)
        LDA4(af1, 0, 1, col1);
        STG_B(0, k2, 2);
        BAR(); MFMA12(af1, bf1, 4); WAITV3(); BAR();
        // P5: buf1 Ah0/ks0; stage buf0.A c0,c1 (k2)
        LDA4(af0, 16384, 0, col0); LDB3(bf0, 12288, col0);
        STG_A(0, k2, 0); STG_A(0, k2, 1);
        BAR(); MFMA12(af0, bf0, 0); BAR();
        // P6: Ah0/ks1; stage buf0.A c2,c3
        LDA4(af1, 16384, 0, col1); LDB3(bf1, 12288, col1);
        STG_A(0, k2, 2); STG_A(0, k2, 3);
        BAR(); MFMA12(af1, bf1, 0); BAR();
        // P7: Ah1/ks0; stage buf1.B c0,c1 (k3)
        LDA4(af0, 16384, 1, col0);
        STG_B(1, k3, 0); STG_B(1, k3, 1);
        BAR(); MFMA12(af0, bf0, 4); BAR();
        // P8: Ah1/ks1; stage buf1.B c2; wait: k2 landed
        LDA4(af1, 16384, 1, col1);
        STG_B(1, k3, 2);
        BAR(); MFMA12(af1, bf1, 4); WAITV3(); BAR();
    }
    // t = 7 peeled: buf0 = K14, buf1 = K15 (B staged at t=6); stage only K15.A
    LDA4(af0, 0, 0, col0); LDB3(bf0, 0, col0);
    STG_A(1, 15, 0); STG_A(1, 15, 1);
    BAR(); MFMA12(af0, bf0, 0); BAR();
    LDA4(af1, 0, 0, col1); LDB3(bf1, 0, col1);
    STG_A(1, 15, 2); STG_A(1, 15, 3);
    BAR(); MFMA12(af1, bf1, 0); BAR();
    LDA4(af0, 0, 1, col0);
    BAR(); MFMA12(af0, bf0, 4); BAR();
    LDA4(af1, 0, 1, col1);
    BAR(); MFMA12(af1, bf1, 4); WAITV0(); BAR();   // K15 fully landed
    LDA4(af0, 16384, 0, col0); LDB3(bf0, 12288, col0);
    BAR(); MFMA12(af0, bf0, 0); BAR();
    LDA4(af1, 16384, 0, col1); LDB3(bf1, 12288, col1);
    BAR(); MFMA12(af1, bf1, 0); BAR();
    LDA4(af0, 16384, 1, col0);
    BAR(); MFMA12(af0, bf0, 4); BAR();
    LDA4(af1, 16384, 1, col1);
    BAR(); MFMA12(af1, bf1, 4);

    // epilogue: C/D layout col=lane&15, row=(lane>>4)*4+reg; stride 3072, no routing
    const int ocol0 = bcol + wc * 48;
    const int orow0 = brow + (wr << 7);
    #pragma unroll
    for (int i = 0; i < 8; ++i)
        #pragma unroll
        for (int j = 0; j < 3; ++j)
            #pragma unroll
            for (int r = 0; r < 4; ++r) {
                const int row = orow0 + i * 16 + fg * 4 + r;
                const int col = ocol0 + j * 16 + fr;
                QKV[(size_t)row * 3072 + col] = f2b(acc[i][j][r]);
            }
#undef STG_A
#undef STG_B
#undef LDA4
#undef LDB3
}

// ---------------- 128x128-tile bf16 GEMM core (m97 structure), K=1024 ----------------
__device__ __forceinline__ void gemm_core_1024(const u16* __restrict__ A,
                                               const u16* __restrict__ B,
                                               int brow, int bcol,
                                               u16* Asb, u16* Bsb,
                                               f32x4 acc[4][4]) {
    const int tid  = threadIdx.x;
    const int lane = tid & 63;
    const int wid  = tid >> 6;
    const int wrow = (wid >> 1) << 6;
    const int wcol = (wid & 1) << 6;
    const int fr   = lane & 15;
    const int fk   = (lane >> 4) << 3;

    const size_t aBase = (size_t)(brow + (tid >> 2)) * 1024 + ((tid & 3) << 3);
    const size_t bBase = (size_t)(bcol + (tid >> 2)) * 1024 + ((tid & 3) << 3);
    const int wOff = wid << 10;

    const f32x4 z = {0.f, 0.f, 0.f, 0.f};
    #pragma unroll
    for (int i = 0; i < 4; ++i)
        #pragma unroll
        for (int j = 0; j < 4; ++j) acc[i][j] = z;

#define STAGE(bufi, kt) do { \
        const u16* ga_ = A + aBase + ((size_t)(kt) << 5); \
        const u16* gb_ = B + bBase + ((size_t)(kt) << 5); \
        char* la_ = (char*)(Asb + ((bufi) << 12)) + wOff; \
        char* lb_ = (char*)(Bsb + ((bufi) << 12)) + wOff; \
        GLL(ga_, la_); GLL(ga_ + (size_t)64 * 1024, la_ + 4096); \
        GLL(gb_, lb_); GLL(gb_ + (size_t)64 * 1024, lb_ + 4096); \
    } while (0)

    STAGE(0, 0);
    #pragma unroll 2
    for (int kt = 0; kt < 32; ++kt) {
        const int buf = kt & 1;
        __syncthreads();
        if (kt + 1 < 32) STAGE(buf ^ 1, kt + 1);
        const u16* As = Asb + (buf << 12);
        const u16* Bs = Bsb + (buf << 12);
        bf16x8 af[4], bfr[4];
        #pragma unroll
        for (int i = 0; i < 4; ++i)
            af[i] = *(const bf16x8*)(As + ((wrow + (i << 4) + fr) << 5) + fk);
        #pragma unroll
        for (int j = 0; j < 4; ++j)
            bfr[j] = *(const bf16x8*)(Bs + ((wcol + (j << 4) + fr) << 5) + fk);
        #pragma unroll
        for (int i = 0; i < 4; ++i)
            #pragma unroll
            for (int j = 0; j < 4; ++j)
                acc[i][j] = __builtin_amdgcn_mfma_f32_16x16x32_bf16(af[i], bfr[j], acc[i][j], 0, 0, 0);
    }
#undef STAGE
}

__global__ __launch_bounds__(256) void gemm_out(const u16* __restrict__ A,
                                                const u16* __restrict__ B,
                                                float* __restrict__ C) {
    __shared__ __align__(16) u16 As[2 * 128 * 32];
    __shared__ __align__(16) u16 Bs[2 * 128 * 32];
    const int brow = blockIdx.y << 7;
    const int bcol = blockIdx.x << 7;
    f32x4 acc[4][4];
    gemm_core_1024(A, B, brow, bcol, As, Bs, acc);

    const int lane = threadIdx.x & 63;
    const int wid  = threadIdx.x >> 6;
    const int wrow = (wid >> 1) << 6;
    const int wcol = (wid & 1) << 6;
    const int g = lane >> 4, c = lane & 15;
    #pragma unroll
    for (int i = 0; i < 4; ++i)
        #pragma unroll
        for (int j = 0; j < 4; ++j)
            #pragma unroll
            for (int r = 0; r < 4; ++r) {
                const int row = brow + wrow + i * 16 + g * 4 + r;
                const int col = bcol + wcol + j * 16 + c;
                C[(size_t)row * 1024 + col] = acc[i][j][r];
            }
}

// ---------------- sliding-window attention ----------------
// Q/K/V live in one [4096][3072] buffer (col blocks 0/1024/2048), row stride 3072.
__global__ __launch_bounds__(256) void attn_kernel(const u16* __restrict__ QKV,
                                                   u16* __restrict__ Og) {
    const int qb  = blockIdx.x;
    const int h   = blockIdx.y;
    const int tid = threadIdx.x;
    const int lane = tid & 63;
    const int w  = tid >> 6;
    const int fr = lane & 15;
    const int fg = lane >> 4;

    __shared__ __align__(16) u16 QK[64 * 72 + 128 * 72];
    __shared__ __align__(16) u16 Vt[64 * 138];   // stride 138 (odd word stride): write conflicts 16->~2-way
    __shared__ float Mrow[64][4];
    __shared__ float Lrow[64][4];

    u16* Qs = QK;
    u16* Ks = QK + 64 * 72;
    u16* Ps = QK;

    const u16* Qg = QKV;
    const u16* Kg = QKV + 1024;
    const u16* Vg = QKV + 2048;

    const int hoff  = h * 64;
    const int qrow0 = qb * 64;
    const int krow0 = qrow0 - 64;

    {
        const int r  = tid >> 3;
        const int c0 = (tid & 7) * 8;
        #pragma unroll
        for (int it = 0; it < 2; ++it) {
            const int row = r + it * 32;
            u16x8 val = *(const u16x8*)(Qg + (size_t)(qrow0 + row) * 3072 + hoff + c0);
            u16x8 o;
            #pragma unroll
            for (int e = 0; e < 8; ++e) o[e] = f2b(b2f(val[e]) * 0.125f);
            *(u16x8*)(Qs + row * 72 + c0) = o;
        }
        #pragma unroll
        for (int it = 0; it < 4; ++it) {
            const int row  = r + it * 32;
            const int grow = krow0 + row;
            u16x8 val = {0, 0, 0, 0, 0, 0, 0, 0};
            if (grow >= 0) val = *(const u16x8*)(Kg + (size_t)grow * 3072 + hoff + c0);
            *(u16x8*)(Ks + row * 72 + c0) = val;
        }
        #pragma unroll
        for (int it = 0; it < 4; ++it) {
            const int j    = r + it * 32;
            const int grow = krow0 + j;
            u16x8 val = {0, 0, 0, 0, 0, 0, 0, 0};
            if (grow >= 0) val = *(const u16x8*)(Vg + (size_t)grow * 3072 + hoff + c0);
            #pragma unroll
            for (int e = 0; e < 8; ++e) Vt[(c0 + e) * 138 + j] = val[e];
        }
    }
    __syncthreads();

    const f32x4 z = {0.f, 0.f, 0.f, 0.f};
    f32x4 s[4][2];
    #pragma unroll
    for (int i = 0; i < 4; ++i) { s[i][0] = z; s[i][1] = z; }
    #pragma unroll
    for (int kk = 0; kk < 2; ++kk) {
        const int k0 = kk * 32 + fg * 8;
        bf16x8 aq[4];
        #pragma unroll
        for (int i = 0; i < 4; ++i)
            aq[i] = *(const bf16x8*)(Qs + (i * 16 + fr) * 72 + k0);
        #pragma unroll
        for (int n = 0; n < 2; ++n) {
            const bf16x8 bk = *(const bf16x8*)(Ks + (w * 32 + n * 16 + fr) * 72 + k0);
            #pragma unroll
            for (int i = 0; i < 4; ++i)
                s[i][n] = __builtin_amdgcn_mfma_f32_16x16x32_bf16(aq[i], bk, s[i][n], 0, 0, 0);
        }
    }

    #pragma unroll
    for (int i = 0; i < 4; ++i) {
        #pragma unroll
        for (int r = 0; r < 4; ++r) {
            const int irow = i * 16 + fg * 4 + r;
            float mx = -3.0e38f;
            #pragma unroll
            for (int n = 0; n < 2; ++n) {
                const int jcol = w * 32 + n * 16 + fr;
                const bool valid = (jcol >= irow + 1) && (jcol <= irow + 64) && (krow0 + jcol >= 0);
                const float v = valid ? s[i][n][r] : -3.0e38f;
                s[i][n][r] = v;
                mx = fmaxf(mx, v);
            }
            #pragma unroll
            for (int d = 1; d < 16; d <<= 1) mx = fmaxf(mx, __shfl_xor(mx, d));
            if (fr == 0) Mrow[irow][w] = mx;
        }
    }
    __syncthreads();

    #pragma unroll
    for (int i = 0; i < 4; ++i) {
        #pragma unroll
        for (int r = 0; r < 4; ++r) {
            const int irow = i * 16 + fg * 4 + r;
            const float M = fmaxf(fmaxf(Mrow[irow][0], Mrow[irow][1]),
                                  fmaxf(Mrow[irow][2], Mrow[irow][3]));
            float sum = 0.f;
            #pragma unroll
            for (int n = 0; n < 2; ++n) {
                const float v = s[i][n][r];
                const float p = (v > -1.0e38f) ? __expf(v - M) : 0.f;
                sum += p;
                Ps[irow * 136 + (w * 32 + n * 16 + fr)] = f2b(p);
            }
            #pragma unroll
            for (int d = 1; d < 16; d <<= 1) sum += __shfl_xor(sum, d);
            if (fr == 0) Lrow[irow][w] = sum;
        }
    }
    __syncthreads();

    f32x4 o[4] = {z, z, z, z};
    #pragma unroll
    for (int ks = 0; ks < 4; ++ks) {
        const int k0 = ks * 32 + fg * 8;
        const bf16x8 ap = *(const bf16x8*)(Ps + (w * 16 + fr) * 136 + k0);
        #pragma unroll
        for (int n = 0; n < 4; ++n) {
            const bf16x8 bv = *(const bf16x8*)(Vt + (n * 16 + fr) * 138 + k0);
            o[n] = __builtin_amdgcn_mfma_f32_16x16x32_bf16(ap, bv, o[n], 0, 0, 0);
        }
    }

    #pragma unroll
    for (int r = 0; r < 4; ++r) {
        const int irow = w * 16 + fg * 4 + r;
        const float L = Lrow[irow][0] + Lrow[irow][1] + Lrow[irow][2] + Lrow[irow][3];
        const float rl = 1.0f / L;
        #pragma unroll
        for (int n = 0; n < 4; ++n)
            Og[(size_t)(qrow0 + irow) * DM + hoff + n * 16 + fr] = f2b(o[n][r] * rl);
    }
}

extern "C" void kernel_launch(void* const* d_in, const int* in_sizes, int n_in,
                              void* d_out, int out_size, void* d_ws, size_t ws_size,
                              hipStream_t stream) {
    (void)in_sizes; (void)n_in; (void)out_size; (void)ws_size;
    const float* x  = (const float*)d_in[0];
    const float* Wq = (const float*)d_in[1];
    const float* Wk = (const float*)d_in[2];
    const float* Wv = (const float*)d_in[3];
    const float* Wo = (const float*)d_in[4];
    float* out = (float*)d_out;

    char* ws = (char*)d_ws;
    u16* xb   = (u16*)(ws);                             // 8 MB  [4096][1024]
    u16* Wqkv = (u16*)(ws + ((size_t)8  << 20));        // 6 MB  [3072][1024]
    u16* Wob  = (u16*)(ws + ((size_t)14 << 20));        // 2 MB
    u16* qkvb = (u16*)(ws + ((size_t)16 << 20));        // 24 MB [4096][3072] (Q|K|V)
    u16* ab   = (u16*)(ws + ((size_t)40 << 20));        // 8 MB  attention output

    cvt_all<<<4096, 256, 0, stream>>>(x, Wq, Wk, Wv, Wo, xb, Wqkv, Wob);
    gemm_qkv8<<<dim3(16, 16), 512, 0, stream>>>(xb, Wqkv, qkvb);
    attn_kernel<<<dim3(64, 16), 256, 0, stream>>>(qkvb, ab);
    gemm_out<<<dim3(8, 32), 256, 0, stream>>>(ab, Wob, out);
}

// Round 5
// 80.788 us; speedup vs baseline: 3.5240x; 1.0605x over previous
//
#include <hip/hip_runtime.h>
#include <cstdint>

typedef unsigned short u16;
using bf16x8 = __attribute__((ext_vector_type(8))) short;
using u16x8  = __attribute__((ext_vector_type(8))) unsigned short;
using f32x4  = __attribute__((ext_vector_type(4))) float;

#define DM 1024

__device__ __forceinline__ u16 f2b(float f) {
    union { float f; unsigned u; } v; v.f = f;
    unsigned r = v.u + 0x7FFFu + ((v.u >> 16) & 1u);   // round-to-nearest-even
    return (u16)(r >> 16);
}
__device__ __forceinline__ float b2f(u16 b) {
    union { unsigned u; float f; } v; v.u = ((unsigned)b) << 16;
    return v.f;
}

#define GLL(gp, lp) __builtin_amdgcn_global_load_lds( \
    (const __attribute__((address_space(1))) void*)(uintptr_t)(gp), \
    (__attribute__((address_space(3))) void*)(unsigned)(uintptr_t)(lp), 16, 0, 0)

#define BAR()    __builtin_amdgcn_s_barrier()
#define WAITV3() asm volatile("s_waitcnt vmcnt(3)" ::: "memory")
#define WAITV0() asm volatile("s_waitcnt vmcnt(0)" ::: "memory")

// ---------------- fused f32 -> bf16 convert for all 5 inputs ----------------
__global__ __launch_bounds__(256) void cvt_all(const float* __restrict__ x,
                                               const float* __restrict__ Wq,
                                               const float* __restrict__ Wk,
                                               const float* __restrict__ Wv,
                                               const float* __restrict__ Wo,
                                               u16* __restrict__ xb,
                                               u16* __restrict__ wqkv,
                                               u16* __restrict__ wob) {
    size_t v = ((size_t)blockIdx.x * 256 + threadIdx.x) << 3;
    const float* src; u16* dst; size_t off;
    if (v < (size_t)4194304) { src = x; dst = xb; off = v; }
    else {
        size_t w = v - 4194304; int s = (int)(w >> 20); off = w & 1048575;
        src = (s == 0) ? Wq : (s == 1) ? Wk : (s == 2) ? Wv : Wo;
        dst = (s < 3) ? (wqkv + ((size_t)s << 20)) : wob;
    }
    const f32x4* p = (const f32x4*)(src + off);
    f32x4 a = p[0], b = p[1];
    u16x8 o;
    o[0] = f2b(a[0]); o[1] = f2b(a[1]); o[2] = f2b(a[2]); o[3] = f2b(a[3]);
    o[4] = f2b(b[0]); o[5] = f2b(b[1]); o[6] = f2b(b[2]); o[7] = f2b(b[3]);
    *(u16x8*)(dst + off) = o;
}

// ---------------- 256x192-tile 8-phase bf16 GEMM, K=1024 ----------------
#define MROW3(af_, bf_, d) \
    acc[d][0] = __builtin_amdgcn_mfma_f32_16x16x32_bf16(af_, bf_[0], acc[d][0], 0, 0, 0); \
    acc[d][1] = __builtin_amdgcn_mfma_f32_16x16x32_bf16(af_, bf_[1], acc[d][1], 0, 0, 0); \
    acc[d][2] = __builtin_amdgcn_mfma_f32_16x16x32_bf16(af_, bf_[2], acc[d][2], 0, 0, 0);

#define MFMA12(af_, bf_, ib) do { \
    __builtin_amdgcn_s_setprio(1); \
    MROW3(af_[0], bf_, (ib) + 0) \
    MROW3(af_[1], bf_, (ib) + 1) \
    MROW3(af_[2], bf_, (ib) + 2) \
    MROW3(af_[3], bf_, (ib) + 3) \
    __builtin_amdgcn_s_setprio(0); } while (0)

__global__ __launch_bounds__(512, 2) void gemm_qkv8(const u16* __restrict__ A,
                                                    const u16* __restrict__ B,
                                                    u16* __restrict__ QKV) {
    __shared__ __align__(16) u16 As[2 * 16384];   // 64 KB: [buf][256 rows][64]
    __shared__ __align__(16) u16 Bs[2 * 12288];   // 48 KB: [buf][192 rows][64]
    const int tid  = threadIdx.x;
    const int lane = tid & 63;
    const int wid  = tid >> 6;
    const int wr   = wid >> 2;
    const int wc   = wid & 3;
    const int fr   = lane & 15;
    const int fg   = lane >> 4;

    const int hw   = blockIdx.y * 16 + blockIdx.x;
    const int lg   = (hw & 7) * 32 + (hw >> 3);
    const int brow = (lg >> 4) << 8;
    const int bcol = (lg & 15) * 192;

    const int srow = tid >> 3;
    const int scol = ((tid & 7) ^ (srow & 7)) << 3;
    const u16* Ag = A + (size_t)(brow + srow) * 1024 + scol;
    const u16* Bg = B + (size_t)(bcol + srow) * 1024 + scol;

#define STG_A(buf, kt, c) GLL(Ag + (size_t)(c) * 65536 + (kt) * 64, \
                              (char*)As + (buf) * 32768 + (c) * 8192 + (wid << 10))
#define STG_B(buf, kt, c) GLL(Bg + (size_t)(c) * 65536 + (kt) * 64, \
                              (char*)Bs + (buf) * 24576 + (c) * 8192 + (wid << 10))

    const int swz  = (fr & 7) << 3;
    const int col0 = (fg << 3) ^ swz;
    const int col1 = (32 + (fg << 3)) ^ swz;
    const int aro  = ((wr << 7) + fr) << 6;
    const int bro  = ((wc * 48) + fr) << 6;

#define LDA4(dst, bufo, ih, cl) do { \
    const u16* p_ = As + (bufo) + aro + ((ih) << 12) + (cl); \
    dst[0] = *(const bf16x8*)(p_); \
    dst[1] = *(const bf16x8*)(p_ + 1024); \
    dst[2] = *(const bf16x8*)(p_ + 2048); \
    dst[3] = *(const bf16x8*)(p_ + 3072); } while (0)

#define LDB3(dst, bufo, cl) do { \
    const u16* p_ = Bs + (bufo) + bro + (cl); \
    dst[0] = *(const bf16x8*)(p_); \
    dst[1] = *(const bf16x8*)(p_ + 1024); \
    dst[2] = *(const bf16x8*)(p_ + 2048); } while (0)

    f32x4 acc[8][3];
    const f32x4 z = {0.f, 0.f, 0.f, 0.f};
    #pragma unroll
    for (int i = 0; i < 8; ++i)
        #pragma unroll
        for (int j = 0; j < 3; ++j) acc[i][j] = z;

    bf16x8 af0[4], af1[4], bf0[3], bf1[3];

    STG_B(0, 0, 0); STG_B(0, 0, 1); STG_B(0, 0, 2);
    STG_A(0, 0, 0); STG_A(0, 0, 1); STG_A(0, 0, 2); STG_A(0, 0, 3);
    STG_B(1, 1, 0); STG_B(1, 1, 1); STG_B(1, 1, 2);
    WAITV3();
    BAR();

    #pragma unroll 1
    for (int t = 0; t < 7; ++t) {
        const int k1 = 2 * t + 1, k2 = 2 * t + 2, k3 = 2 * t + 3;
        LDA4(af0, 0, 0, col0); LDB3(bf0, 0, col0);
        STG_A(1, k1, 0); STG_A(1, k1, 1);
        BAR(); MFMA12(af0, bf0, 0); BAR();
        LDA4(af1, 0, 0, col1); LDB3(bf1, 0, col1);
        STG_A(1, k1, 2); STG_A(1, k1, 3);
        BAR(); MFMA12(af1, bf1, 0); BAR();
        LDA4(af0, 0, 1, col0);
        STG_B(0, k2, 0); STG_B(0, k2, 1);
        BAR(); MFMA12(af0, bf0, 4); BAR();
        LDA4(af1, 0, 1, col1);
        STG_B(0, k2, 2);
        BAR(); MFMA12(af1, bf1, 4); WAITV3(); BAR();
        LDA4(af0, 16384, 0, col0); LDB3(bf0, 12288, col0);
        STG_A(0, k2, 0); STG_A(0, k2, 1);
        BAR(); MFMA12(af0, bf0, 0); BAR();
        LDA4(af1, 16384, 0, col1); LDB3(bf1, 12288, col1);
        STG_A(0, k2, 2); STG_A(0, k2, 3);
        BAR(); MFMA12(af1, bf1, 0); BAR();
        LDA4(af0, 16384, 1, col0);
        STG_B(1, k3, 0); STG_B(1, k3, 1);
        BAR(); MFMA12(af0, bf0, 4); BAR();
        LDA4(af1, 16384, 1, col1);
        STG_B(1, k3, 2);
        BAR(); MFMA12(af1, bf1, 4); WAITV3(); BAR();
    }
    LDA4(af0, 0, 0, col0); LDB3(bf0, 0, col0);
    STG_A(1, 15, 0); STG_A(1, 15, 1);
    BAR(); MFMA12(af0, bf0, 0); BAR();
    LDA4(af1, 0, 0, col1); LDB3(bf1, 0, col1);
    STG_A(1, 15, 2); STG_A(1, 15, 3);
    BAR(); MFMA12(af1, bf1, 0); BAR();
    LDA4(af0, 0, 1, col0);
    BAR(); MFMA12(af0, bf0, 4); BAR();
    LDA4(af1, 0, 1, col1);
    BAR(); MFMA12(af1, bf1, 4); WAITV0(); BAR();
    LDA4(af0, 16384, 0, col0); LDB3(bf0, 12288, col0);
    BAR(); MFMA12(af0, bf0, 0); BAR();
    LDA4(af1, 16384, 0, col1); LDB3(bf1, 12288, col1);
    BAR(); MFMA12(af1, bf1, 0); BAR();
    LDA4(af0, 16384, 1, col0);
    BAR(); MFMA12(af0, bf0, 4); BAR();
    LDA4(af1, 16384, 1, col1);
    BAR(); MFMA12(af1, bf1, 4);

    const int ocol0 = bcol + wc * 48;
    const int orow0 = brow + (wr << 7);
    #pragma unroll
    for (int i = 0; i < 8; ++i)
        #pragma unroll
        for (int j = 0; j < 3; ++j)
            #pragma unroll
            for (int r = 0; r < 4; ++r) {
                const int row = orow0 + i * 16 + fg * 4 + r;
                const int col = ocol0 + j * 16 + fr;
                QKV[(size_t)row * 3072 + col] = f2b(acc[i][j][r]);
            }
#undef STG_A
#undef STG_B
#undef LDA4
#undef LDB3
}

// ---------------- gemm_out_v2: 128x64 tile, BK=64, 512 blocks (2/CU) ----------------
// C[4096][1024] f32 = A[4096][1024]bf16 @ B[1024][1024]bf16^T.
// 256 threads = 4 waves (2M x 2N); wave owns 64x32. Swizzled LDS (qkv8 pattern).
__global__ __launch_bounds__(256) void gemm_out(const u16* __restrict__ A,
                                                const u16* __restrict__ B,
                                                float* __restrict__ C) {
    __shared__ __align__(16) u16 As[2 * 8192];   // 32 KB: [buf][128][64]
    __shared__ __align__(16) u16 Bs[2 * 4096];   // 16 KB: [buf][64][64]
    const int tid  = threadIdx.x;
    const int lane = tid & 63;
    const int wid  = tid >> 6;
    const int wr   = wid >> 1;          // 0..1
    const int wc   = wid & 1;           // 0..1
    const int fr   = lane & 15;
    const int fg   = lane >> 4;

    // bijective XCD swizzle over 512 blocks: each XCD gets 64 consecutive tiles
    // (4 M-panels x 16 N-tiles -> A panels L2-resident per XCD)
    const int hw   = blockIdx.y * 16 + blockIdx.x;
    const int lg   = (hw & 7) * 64 + (hw >> 3);
    const int brow = (lg >> 4) << 7;    // M-tile * 128
    const int bcol = (lg & 15) << 6;    // N-tile * 64

    const int srow = tid >> 3;                        // 0..31
    const int scol = ((tid & 7) ^ (srow & 7)) << 3;   // pre-swizzled source col
    const u16* Ag = A + (size_t)(brow + srow) * 1024 + scol;
    const u16* Bg = B + (size_t)(bcol + srow) * 1024 + scol;

    // chunk = 32 rows x 64 cols = 4 KB = 256 threads x 16B
#define OSTG_A(buf, kt, c) GLL(Ag + (size_t)(c) * 32768 + (kt) * 64, \
                               (char*)As + (buf) * 16384 + (c) * 4096 + (tid << 4))
#define OSTG_B(buf, kt, c) GLL(Bg + (size_t)(c) * 32768 + (kt) * 64, \
                               (char*)Bs + (buf) * 8192 + (c) * 4096 + (tid << 4))
#define OSTG(buf, kt) do { \
        OSTG_A(buf, kt, 0); OSTG_A(buf, kt, 1); OSTG_A(buf, kt, 2); OSTG_A(buf, kt, 3); \
        OSTG_B(buf, kt, 0); OSTG_B(buf, kt, 1); } while (0)

    const int swz  = (fr & 7) << 3;
    const int col0 = (fg << 3) ^ swz;          // k-step 0
    const int col1 = (32 + (fg << 3)) ^ swz;   // k-step 1
    const int aro  = ((wr << 6) + fr) << 6;    // (wr*64+fr)*64
    const int bro  = ((wc << 5) + fr) << 6;    // (wc*32+fr)*64

    f32x4 acc[4][2];
    const f32x4 z = {0.f, 0.f, 0.f, 0.f};
    #pragma unroll
    for (int i = 0; i < 4; ++i) { acc[i][0] = z; acc[i][1] = z; }

    OSTG(0, 0);
    #pragma unroll 2
    for (int kt = 0; kt < 16; ++kt) {
        const int buf = kt & 1;
        __syncthreads();                  // staged buf ready; prior reads drained
        if (kt + 1 < 16) OSTG(buf ^ 1, kt + 1);
        const u16* Ab = As + (buf << 13);
        const u16* Bb = Bs + (buf << 12);
        bf16x8 a0[4], a1[4], b0[2], b1[2];
        #pragma unroll
        for (int i = 0; i < 4; ++i) {
            a0[i] = *(const bf16x8*)(Ab + aro + (i << 10) + col0);
            a1[i] = *(const bf16x8*)(Ab + aro + (i << 10) + col1);
        }
        #pragma unroll
        for (int j = 0; j < 2; ++j) {
            b0[j] = *(const bf16x8*)(Bb + bro + (j << 10) + col0);
            b1[j] = *(const bf16x8*)(Bb + bro + (j << 10) + col1);
        }
        #pragma unroll
        for (int i = 0; i < 4; ++i)
            #pragma unroll
            for (int j = 0; j < 2; ++j) {
                acc[i][j] = __builtin_amdgcn_mfma_f32_16x16x32_bf16(a0[i], b0[j], acc[i][j], 0, 0, 0);
                acc[i][j] = __builtin_amdgcn_mfma_f32_16x16x32_bf16(a1[i], b1[j], acc[i][j], 0, 0, 0);
            }
    }
#undef OSTG_A
#undef OSTG_B
#undef OSTG

    // epilogue: C/D layout col=lane&15, row=(lane>>4)*4+reg
    #pragma unroll
    for (int i = 0; i < 4; ++i)
        #pragma unroll
        for (int j = 0; j < 2; ++j)
            #pragma unroll
            for (int r = 0; r < 4; ++r) {
                const int row = brow + wr * 64 + i * 16 + fg * 4 + r;
                const int col = bcol + wc * 32 + j * 16 + fr;
                C[(size_t)row * 1024 + col] = acc[i][j][r];
            }
}

// ---------------- sliding-window attention ----------------
// Q/K/V live in one [4096][3072] buffer (col blocks 0/1024/2048), row stride 3072.
__global__ __launch_bounds__(256) void attn_kernel(const u16* __restrict__ QKV,
                                                   u16* __restrict__ Og) {
    const int qb  = blockIdx.x;
    const int h   = blockIdx.y;
    const int tid = threadIdx.x;
    const int lane = tid & 63;
    const int w  = tid >> 6;
    const int fr = lane & 15;
    const int fg = lane >> 4;

    __shared__ __align__(16) u16 QK[64 * 72 + 128 * 72];
    __shared__ __align__(16) u16 Vt[64 * 138];
    __shared__ float Mrow[64][4];
    __shared__ float Lrow[64][4];

    u16* Qs = QK;
    u16* Ks = QK + 64 * 72;
    u16* Ps = QK;

    const u16* Qg = QKV;
    const u16* Kg = QKV + 1024;
    const u16* Vg = QKV + 2048;

    const int hoff  = h * 64;
    const int qrow0 = qb * 64;
    const int krow0 = qrow0 - 64;

    {
        const int r  = tid >> 3;
        const int c0 = (tid & 7) * 8;
        #pragma unroll
        for (int it = 0; it < 2; ++it) {
            const int row = r + it * 32;
            u16x8 val = *(const u16x8*)(Qg + (size_t)(qrow0 + row) * 3072 + hoff + c0);
            u16x8 o;
            #pragma unroll
            for (int e = 0; e < 8; ++e) o[e] = f2b(b2f(val[e]) * 0.125f);
            *(u16x8*)(Qs + row * 72 + c0) = o;
        }
        #pragma unroll
        for (int it = 0; it < 4; ++it) {
            const int row  = r + it * 32;
            const int grow = krow0 + row;
            u16x8 val = {0, 0, 0, 0, 0, 0, 0, 0};
            if (grow >= 0) val = *(const u16x8*)(Kg + (size_t)grow * 3072 + hoff + c0);
            *(u16x8*)(Ks + row * 72 + c0) = val;
        }
        #pragma unroll
        for (int it = 0; it < 4; ++it) {
            const int j    = r + it * 32;
            const int grow = krow0 + j;
            u16x8 val = {0, 0, 0, 0, 0, 0, 0, 0};
            if (grow >= 0) val = *(const u16x8*)(Vg + (size_t)grow * 3072 + hoff + c0);
            #pragma unroll
            for (int e = 0; e < 8; ++e) Vt[(c0 + e) * 138 + j] = val[e];
        }
    }
    __syncthreads();

    const f32x4 z = {0.f, 0.f, 0.f, 0.f};
    f32x4 s[4][2];
    #pragma unroll
    for (int i = 0; i < 4; ++i) { s[i][0] = z; s[i][1] = z; }
    #pragma unroll
    for (int kk = 0; kk < 2; ++kk) {
        const int k0 = kk * 32 + fg * 8;
        bf16x8 aq[4];
        #pragma unroll
        for (int i = 0; i < 4; ++i)
            aq[i] = *(const bf16x8*)(Qs + (i * 16 + fr) * 72 + k0);
        #pragma unroll
        for (int n = 0; n < 2; ++n) {
            const bf16x8 bk = *(const bf16x8*)(Ks + (w * 32 + n * 16 + fr) * 72 + k0);
            #pragma unroll
            for (int i = 0; i < 4; ++i)
                s[i][n] = __builtin_amdgcn_mfma_f32_16x16x32_bf16(aq[i], bk, s[i][n], 0, 0, 0);
        }
    }

    #pragma unroll
    for (int i = 0; i < 4; ++i) {
        #pragma unroll
        for (int r = 0; r < 4; ++r) {
            const int irow = i * 16 + fg * 4 + r;
            float mx = -3.0e38f;
            #pragma unroll
            for (int n = 0; n < 2; ++n) {
                const int jcol = w * 32 + n * 16 + fr;
                const bool valid = (jcol >= irow + 1) && (jcol <= irow + 64) && (krow0 + jcol >= 0);
                const float v = valid ? s[i][n][r] : -3.0e38f;
                s[i][n][r] = v;
                mx = fmaxf(mx, v);
            }
            #pragma unroll
            for (int d = 1; d < 16; d <<= 1) mx = fmaxf(mx, __shfl_xor(mx, d));
            if (fr == 0) Mrow[irow][w] = mx;
        }
    }
    __syncthreads();

    #pragma unroll
    for (int i = 0; i < 4; ++i) {
        #pragma unroll
        for (int r = 0; r < 4; ++r) {
            const int irow = i * 16 + fg * 4 + r;
            const float M = fmaxf(fmaxf(Mrow[irow][0], Mrow[irow][1]),
                                  fmaxf(Mrow[irow][2], Mrow[irow][3]));
            float sum = 0.f;
            #pragma unroll
            for (int n = 0; n < 2; ++n) {
                const float v = s[i][n][r];
                const float p = (v > -1.0e38f) ? __expf(v - M) : 0.f;
                sum += p;
                Ps[irow * 136 + (w * 32 + n * 16 + fr)] = f2b(p);
            }
            #pragma unroll
            for (int d = 1; d < 16; d <<= 1) sum += __shfl_xor(sum, d);
            if (fr == 0) Lrow[irow][w] = sum;
        }
    }
    __syncthreads();

    f32x4 o[4] = {z, z, z, z};
    #pragma unroll
    for (int ks = 0; ks < 4; ++ks) {
        const int k0 = ks * 32 + fg * 8;
        const bf16x8 ap = *(const bf16x8*)(Ps + (w * 16 + fr) * 136 + k0);
        #pragma unroll
        for (int n = 0; n < 4; ++n) {
            const bf16x8 bv = *(const bf16x8*)(Vt + (n * 16 + fr) * 138 + k0);
            o[n] = __builtin_amdgcn_mfma_f32_16x16x32_bf16(ap, bv, o[n], 0, 0, 0);
        }
    }

    #pragma unroll
    for (int r = 0; r < 4; ++r) {
        const int irow = w * 16 + fg * 4 + r;
        const float L = Lrow[irow][0] + Lrow[irow][1] + Lrow[irow][2] + Lrow[irow][3];
        const float rl = 1.0f / L;
        #pragma unroll
        for (int n = 0; n < 4; ++n)
            Og[(size_t)(qrow0 + irow) * DM + hoff + n * 16 + fr] = f2b(o[n][r] * rl);
    }
}

extern "C" void kernel_launch(void* const* d_in, const int* in_sizes, int n_in,
                              void* d_out, int out_size, void* d_ws, size_t ws_size,
                              hipStream_t stream) {
    (void)in_sizes; (void)n_in; (void)out_size; (void)ws_size;
    const float* x  = (const float*)d_in[0];
    const float* Wq = (const float*)d_in[1];
    const float* Wk = (const float*)d_in[2];
    const float* Wv = (const float*)d_in[3];
    const float* Wo = (const float*)d_in[4];
    float* out = (float*)d_out;

    char* ws = (char*)d_ws;
    u16* xb   = (u16*)(ws);                             // 8 MB  [4096][1024]
    u16* Wqkv = (u16*)(ws + ((size_t)8  << 20));        // 6 MB  [3072][1024]
    u16* Wob  = (u16*)(ws + ((size_t)14 << 20));        // 2 MB
    u16* qkvb = (u16*)(ws + ((size_t)16 << 20));        // 24 MB [4096][3072] (Q|K|V)
    u16* ab   = (u16*)(ws + ((size_t)40 << 20));        // 8 MB  attention output

    cvt_all<<<4096, 256, 0, stream>>>(x, Wq, Wk, Wv, Wo, xb, Wqkv, Wob);
    gemm_qkv8<<<dim3(16, 16), 512, 0, stream>>>(xb, Wqkv, qkvb);
    attn_kernel<<<dim3(64, 16), 256, 0, stream>>>(qkvb, ab);
    gemm_out<<<dim3(16, 32), 256, 0, stream>>>(ab, Wob, out);
}